// Round 15
// baseline (141.517 us; speedup 1.0000x reference)
//
#include <hip/hip_runtime.h>
#include <hip/hip_bf16.h>
#include <math.h>

// ---- output layout ----
#define OFF_IMU  0
#define OFF_ATOM 19660800
#define OFF_SEG  20160000
#define OFF_FC   20659200
#define OFF_FL   20691968

// ---- ws layout (4-byte elements) ----
#define WS_BRIDGE 0        // 32768 floats  (8192 x 4)
#define WS_TR     32768    // 262144 floats (8192 x 32)
#define WS_ENDS   303104   // 4160 ints
#define WS_STARTS 307264   // 4160 ints
#define WS_NK     311424   // 32 ints

static __device__ __forceinline__ int imin(int a, int b) { return a < b ? a : b; }
static __device__ __forceinline__ int imax(int a, int b) { return a > b ? a : b; }

typedef __attribute__((ext_vector_type(8))) short bf16x8;
typedef __attribute__((ext_vector_type(4))) float f32x4;
union AF { uint32_t u[4]; bf16x8 v; };

// pack fp32 -> (bf16_lo << 16) | bf16_hi, where hi=rne(x), lo=rne(x-hi)
static __device__ __forceinline__ uint32_t pack_hilo(float x)
{
    __hip_bfloat16 h = __float2bfloat16(x);
    const float hf = __bfloat162float(h);
    __hip_bfloat16 lo = __float2bfloat16(x - hf);
    const uint32_t hb = *(const unsigned short*)&h;
    const uint32_t lb = *(const unsigned short*)&lo;
    return hb | (lb << 16);
}

// im2col plane: rows 0..416, stride 21 u32; [row][k] = packed x[ic][row+dt]
#define IMS 21
#define IMROWS 417          // 26 tiles x 16 + pad (tile 25 is wave1's dummy)

// ============================================================================
// K1: conv1d(6->32,k=3,VALID) + ReLU + half-mean-pool + bridge sigmoid MLP
// MFMA im2col version. 8192 blocks x 128 threads; 1 sample/block, 2 waves.
// Split-bf16 (hi/lo) x and w: acc += Ahi*Bhi + Ahi*Blo + Alo*Bhi (fp32-safe,
// verified round 14: absmax 0.0078). im2col materialized in LDS (stride 21,
// odd -> conflict-free lane banks); A-frag = 8 consecutive u32 reads + 8
// v_perm. Wave wv handles 13 tiles (wv=1 includes dummy tile 25 on zeroed
// pad rows, pool-masked). Zero-regions disjoint from staged slots -> one
// staging barrier. C/D layout verified: col=lane&15 (oc), row=(l>>4)*4+reg.
// ============================================================================
__global__ __launch_bounds__(128) void k1_conv_bridge(
    const float* __restrict__ x, const float* __restrict__ conv_w,
    const float* __restrict__ conv_b, const float* __restrict__ W_b1,
    const float* __restrict__ b_b1, float* __restrict__ bridge)
{
    __shared__ uint32_t xd[IMROWS * IMS];     // 8757 u32 = 35.0 KB
    __shared__ float part[2][4][16];
    const int tid = threadIdx.x;
    const int n = blockIdx.x;

    const int wv = tid >> 6;           // wave 0/1 = tile half
    const int l  = tid & 63;
    const int r  = l & 15;             // A row within t-tile / C col (oc)
    const int kb = l >> 4;             // k-octet / C row-group

    // ---- zero-init regions never covered by staging (disjoint -> race-free)
    for (int i = tid; i < 1200; i += 128) {          // cols 18..20, rows 0..399
        const int row = i / 3;
        xd[row * IMS + 18 + (i - row * 3)] = 0;
    }
    for (int i = tid; i < 357; i += 128)             // rows 400..416, all cols
        xd[400 * IMS + i] = 0;
    if (tid < 18) {                                  // rows 398/399 unstaged k
        int row, col;
        if (tid < 6)       { row = 398; col = tid * 3 + 2; }
        else               { const int j = tid - 6; row = 399;
                             col = (j >> 1) * 3 + 1 + (j & 1); }
        xd[row * IMS + col] = 0;
    }

    // ---- stage sample into im2col (each element -> its 3 rows) ----
    {
        const float4* xw = (const float4*)(x + (size_t)n * 2400);
        for (int i = tid; i < 600; i += 128) {
            const float4 v = xw[i];
            const int ic = i / 100;
            const int t4 = (i - ic * 100) * 4;
            const int k3 = ic * 3;
            const float vv[4] = {v.x, v.y, v.z, v.w};
#pragma unroll
            for (int e = 0; e < 4; ++e) {
                const int T = t4 + e;
                const uint32_t u = pack_hilo(vv[e]);
#pragma unroll
                for (int dt = 0; dt < 3; ++dt) {
                    const int row = T - dt;
                    if (row >= 0) xd[row * IMS + k3 + dt] = u;
                }
            }
        }
    }

    // ---- B fragments (weights), loop-invariant: B[k][oc]=w[oc][k] ----
    AF Bhi[2], Blo[2];
    float bias[2];
#pragma unroll
    for (int ot = 0; ot < 2; ++ot) {
        const float* wp = conv_w + (size_t)(r + ot * 16) * 18;
#pragma unroll
        for (int j = 0; j < 4; ++j) {
            const int k0 = kb * 8 + 2 * j, k1 = k0 + 1;
            const float w0 = (k0 < 18) ? wp[k0] : 0.0f;
            const float w1 = (k1 < 18) ? wp[k1] : 0.0f;
            const uint32_t e0 = pack_hilo(w0), e1 = pack_hilo(w1);
            Bhi[ot].u[j] = (e0 & 0xffffu) | (e1 << 16);
            Blo[ot].u[j] = (e0 >> 16) | (e1 & 0xffff0000u);
        }
        bias[ot] = conv_b[r + ot * 16];
    }

    __syncthreads();                   // staged im2col visible to both waves

    // ---- MFMA over 13 tiles (wave base offset keeps imm addressing) ----
    const int tileoff = wv * 13;
    const uint32_t* ab = xd + (size_t)(tileoff * 16 + r) * IMS + kb * 8;
    float p00 = 0.f, p01 = 0.f, p10 = 0.f, p11 = 0.f;

#pragma unroll
    for (int tt = 0; tt < 13; ++tt) {
        uint32_t e[8];
#pragma unroll
        for (int s = 0; s < 8; ++s) e[s] = ab[tt * (16 * IMS) + s];
        AF Ahi, Alo;
#pragma unroll
        for (int j = 0; j < 4; ++j) {
            Ahi.u[j] = __builtin_amdgcn_perm(e[2 * j + 1], e[2 * j], 0x05040100u);
            Alo.u[j] = __builtin_amdgcn_perm(e[2 * j + 1], e[2 * j], 0x07060302u);
        }
        f32x4 acc0 = {0.f, 0.f, 0.f, 0.f};
        f32x4 acc1 = {0.f, 0.f, 0.f, 0.f};
        acc0 = __builtin_amdgcn_mfma_f32_16x16x32_bf16(Ahi.v, Bhi[0].v, acc0, 0, 0, 0);
        acc1 = __builtin_amdgcn_mfma_f32_16x16x32_bf16(Ahi.v, Bhi[1].v, acc1, 0, 0, 0);
        acc0 = __builtin_amdgcn_mfma_f32_16x16x32_bf16(Ahi.v, Blo[0].v, acc0, 0, 0, 0);
        acc1 = __builtin_amdgcn_mfma_f32_16x16x32_bf16(Ahi.v, Blo[1].v, acc1, 0, 0, 0);
        acc0 = __builtin_amdgcn_mfma_f32_16x16x32_bf16(Alo.v, Bhi[0].v, acc0, 0, 0, 0);
        acc1 = __builtin_amdgcn_mfma_f32_16x16x32_bf16(Alo.v, Bhi[1].v, acc1, 0, 0, 0);
#pragma unroll
        for (int reg = 0; reg < 4; ++reg) {
            const int t = (tileoff + tt) * 16 + kb * 4 + reg;
            const float r0 = fmaxf(acc0[reg] + bias[0], 0.0f);
            const float r1 = fmaxf(acc1[reg] + bias[1], 0.0f);
            const bool h0 = t < 199;
            const bool h1 = (t >= 199) && (t < 398);
            p00 += h0 ? r0 : 0.0f;  p01 += h1 ? r0 : 0.0f;
            p10 += h0 ? r1 : 0.0f;  p11 += h1 ? r1 : 0.0f;
        }
    }

    // reduce over the 4 k-octet row-groups
    p00 += __shfl_xor(p00, 16); p00 += __shfl_xor(p00, 32);
    p01 += __shfl_xor(p01, 16); p01 += __shfl_xor(p01, 32);
    p10 += __shfl_xor(p10, 16); p10 += __shfl_xor(p10, 32);
    p11 += __shfl_xor(p11, 16); p11 += __shfl_xor(p11, 32);

    if (l < 16) {
        part[wv][0][l] = p00;  part[wv][1][l] = p01;
        part[wv][2][l] = p10;  part[wv][3][l] = p11;
    }
    __syncthreads();

    // ---- bridge MLP (wave 0): feature f = oc*2 + half ----
    if (tid < 64) {
        const int f = tid;
        const int oc = f >> 1, h = f & 1;
        const int idx = (oc < 16) ? h : (2 + h);
        const int c = oc & 15;
        const float v = (part[0][idx][c] + part[1][idx][c]) * (1.0f / 199.0f);
        const float4 wb = *(const float4*)(W_b1 + f * 4);
        float q0 = v * wb.x, q1 = v * wb.y, q2 = v * wb.z, q3 = v * wb.w;
#pragma unroll
        for (int off = 1; off < 64; off <<= 1) {
            q0 += __shfl_xor(q0, off, 64);
            q1 += __shfl_xor(q1, off, 64);
            q2 += __shfl_xor(q2, off, 64);
            q3 += __shfl_xor(q3, off, 64);
        }
        if (f == 0) {
            float* bp = bridge + (size_t)n * 4;
            bp[0] = 1.0f / (1.0f + __expf(-(q0 + b_b1[0])));
            bp[1] = 1.0f / (1.0f + __expf(-(q1 + b_b1[1])));
            bp[2] = 1.0f / (1.0f + __expf(-(q2 + b_b1[2])));
            bp[3] = 1.0f / (1.0f + __expf(-(q3 + b_b1[3])));
        }
    }
}

// ============================================================================
// K234: forcast+floss (out) + segmentation (local) + attention + transformer.
// grid 256 = (b, 32-query chunk), 256 threads. Each block recomputes the
// per-b segmentation locally; ends/starts/nk written redundantly (same values).
// hb[b,s] = bridge[s*32 + b] (scrambled). exp() select-guarded.
// ============================================================================
__global__ __launch_bounds__(256) void k234_seg_attn(
    const float* __restrict__ bridge, const float* __restrict__ imu_mask,
    const float* __restrict__ W_fc, const float* __restrict__ b_fc,
    const int* __restrict__ imu_len, float* __restrict__ out,
    int* __restrict__ ends_ws, int* __restrict__ starts_ws, int* __restrict__ nk_ws,
    const float* __restrict__ Wqkv, const float* __restrict__ Wo,
    const float* __restrict__ ln1_g, const float* __restrict__ ln1_b,
    const float* __restrict__ Wf1, const float* __restrict__ bf1,
    const float* __restrict__ Wf2, const float* __restrict__ bf2,
    const float* __restrict__ ln2_g, const float* __restrict__ ln2_b,
    const float* __restrict__ Wout, const float* __restrict__ bout,
    float* __restrict__ tr_ws)
{
    const int b = blockIdx.x >> 3;
    const int chunk = blockIdx.x & 7;
    const int tid = threadIdx.x;
    __shared__ float kv[256][8];
    __shared__ int sid[256];
    __shared__ float part[32][8][8];
    __shared__ float fl[256];
    __shared__ float sel[256];
    __shared__ float sp[256];
    __shared__ int pk[256];
    __shared__ int sc[2][256];
    __shared__ int kpl[256];

    // ---- stage K/V for all 256 keys (independent of segmentation) ----
    {
        const float4 h = *(const float4*)(bridge + (size_t)(tid * 32 + b) * 4);
#pragma unroll
        for (int e = 0; e < 4; ++e) {
            kv[tid][e]     = h.x * Wqkv[16 + e] + h.y * Wqkv[20 + e] + h.z * Wqkv[24 + e] + h.w * Wqkv[28 + e];
            kv[tid][4 + e] = h.x * Wqkv[32 + e] + h.y * Wqkv[36 + e] + h.z * Wqkv[40 + e] + h.w * Wqkv[44 + e];
        }
    }

    // ---- forcast + floss (n = b*256 + tid) ----
    {
        const int n = b * 256 + tid;
        float sh[4], cur[4];
#pragma unroll
        for (int j = 0; j < 4; ++j) {
            sh[j] = (tid == 0) ? 0.0f : bridge[(n - 1) * 4 + j];
            cur[j] = bridge[n * 4 + j];
        }
        const float fm = ((tid == 0) ? 0.0f : 1.0f) * imu_mask[n];
        float flv = 0.0f;
#pragma unroll
        for (int j = 0; j < 4; ++j) {
            float f = b_fc[j];
#pragma unroll
            for (int i = 0; i < 4; ++i) f = fmaf(sh[i], W_fc[i * 4 + j], f);
            out[OFF_FC + n * 4 + j] = f;
            const float d = (f - cur[j]) * fm;
            flv = fmaf(d, d, flv);
        }
        flv *= 0.25f;
        const bool lm = (tid >= 2) && (tid < 254);
        flv = (flv > 0.001f && lm) ? flv : 0.0f;
        out[OFF_FL + n] = flv;
        fl[tid] = flv;
        sp[tid] = 0.0f;
    }
    __syncthreads();

    // ---- segmentation (local) ----
    if (tid < 64) {                       // sel: windows of 4, first-max
        const int base = tid * 4;
        float m = fl[base]; int idx = 0;
#pragma unroll
        for (int i = 1; i < 4; ++i) { float v = fl[base + i]; if (v > m) { m = v; idx = i; } }
#pragma unroll
        for (int i = 0; i < 4; ++i) sel[base + i] = (i == idx) ? m : 0.0f;
    }
    __syncthreads();
    if (tid < 63) {                       // sel2 on sel[2:254)
        const int base = 2 + tid * 4;
        float m = sel[base]; int idx = 0;
#pragma unroll
        for (int i = 1; i < 4; ++i) { float v = sel[base + i]; if (v > m) { m = v; idx = i; } }
        sp[base + idx] = (m > 0.0f) ? 1.0f : 0.0f;
    }
    __syncthreads();
    int last = (int)rintf((float)imu_len[b] * (1.0f / 256.0f));  // half-even
    last = imin(imax(last, 2), 256);
    const int point = ((sp[tid] > 0.0f) && (tid < last)) ? 1 : 0;
    pk[tid] = point;
    __syncthreads();
    const int pnext = (tid < 255) ? pk[tid + 1] : 0;
    const int bnd = pnext | ((tid + 1 == last) ? 1 : 0);
    const int kept = (point && !bnd) ? 1 : 0;
    __syncthreads();
    sc[0][tid] = kept;
    __syncthreads();
    int src = 0;                          // Hillis-Steele inclusive scan
    for (int off = 1; off < 256; off <<= 1) {
        const int v = sc[src][tid] + ((tid >= off) ? sc[src][tid - off] : 0);
        sc[src ^ 1][tid] = v;
        __syncthreads();
        src ^= 1;
    }
    const int myid = sc[src][tid];
    sid[tid] = myid;
    const int nk = sc[src][255];
    if (kept) kpl[myid - 1] = tid;
    __syncthreads();
    if (tid < 130) {                      // redundant across the 8 b-blocks
        ends_ws[b * 130 + tid] = (tid < nk) ? kpl[tid] : last;
        starts_ws[b * 130 + tid] = (tid == 0) ? 0 : ((tid - 1 < nk) ? kpl[tid - 1] : last);
    }
    if (tid == 0) nk_ws[b] = nk;

    // ---- attention ----
    const int lq = tid & 31;
    const int jg = tid >> 5;
    const int sq = chunk * 32 + lq;
    {
        const float4 h = *(const float4*)(bridge + (size_t)(sq * 32 + b) * 4);
        float qv[4];
#pragma unroll
        for (int e = 0; e < 4; ++e)
            qv[e] = h.x * Wqkv[e] + h.y * Wqkv[4 + e] + h.z * Wqkv[8 + e] + h.w * Wqkv[12 + e];
        const bool vs = sq < last;
        const int ms = sid[sq];
        const float isq = 0.70710678118654752f;
        float m0 = -1e30f, l0 = 0.f, a00 = 0.f, a01 = 0.f;
        float m1 = -1e30f, l1 = 0.f, a10 = 0.f, a11 = 0.f;
#pragma unroll 4
        for (int jj = 0; jj < 32; ++jj) {
            const int j = jg * 32 + jj;
            const bool allowed = (j == sq) || (vs && (j < last) && (sid[j] == ms));
            const float sc0 = (qv[0] * kv[j][0] + qv[1] * kv[j][1]) * isq;
            const float sc1 = (qv[2] * kv[j][2] + qv[3] * kv[j][3]) * isq;
            {
                const float mn = allowed ? fmaxf(m0, sc0) : m0;
                const float c = __expf(m0 - mn);                      // arg <= 0 always
                const float e = allowed ? __expf(sc0 - mn) : 0.0f;    // select: no inf*0
                l0 = l0 * c + e; a00 = a00 * c + e * kv[j][4]; a01 = a01 * c + e * kv[j][5]; m0 = mn;
            }
            {
                const float mn = allowed ? fmaxf(m1, sc1) : m1;
                const float c = __expf(m1 - mn);
                const float e = allowed ? __expf(sc1 - mn) : 0.0f;
                l1 = l1 * c + e; a10 = a10 * c + e * kv[j][6]; a11 = a11 * c + e * kv[j][7]; m1 = mn;
            }
        }
        float* pp = part[lq][jg];
        pp[0] = m0; pp[1] = l0; pp[2] = a00; pp[3] = a01;
        pp[4] = m1; pp[5] = l1; pp[6] = a10; pp[7] = a11;
    }
    __syncthreads();
    if (tid < 32) {
        const int s = chunk * 32 + tid;
        float M0 = -1e30f, L0 = 0.f, A00 = 0.f, A01 = 0.f;
        float M1 = -1e30f, L1 = 0.f, A10 = 0.f, A11 = 0.f;
#pragma unroll
        for (int p = 0; p < 8; ++p) {
            const float* pp = part[tid][p];
            {
                const float mn = fmaxf(M0, pp[0]);
                const float c0 = __expf(M0 - mn), c1 = __expf(pp[0] - mn);   // args <= 0
                L0 = L0 * c0 + pp[1] * c1; A00 = A00 * c0 + pp[2] * c1; A01 = A01 * c0 + pp[3] * c1; M0 = mn;
            }
            {
                const float mn = fmaxf(M1, pp[4]);
                const float c0 = __expf(M1 - mn), c1 = __expf(pp[4] - mn);
                L1 = L1 * c0 + pp[5] * c1; A10 = A10 * c0 + pp[6] * c1; A11 = A11 * c0 + pp[7] * c1; M1 = mn;
            }
        }
        const float4 h = *(const float4*)(bridge + (size_t)(s * 32 + b) * 4);
        const float hb0 = h.x, hb1 = h.y, hb2 = h.z, hb3 = h.w;
        float ao[4] = {A00 / L0, A01 / L0, A10 / L1, A11 / L1};
        float x1[4];
#pragma unroll
        for (int jj = 0; jj < 4; ++jj)
            x1[jj] = ao[0] * Wo[jj] + ao[1] * Wo[4 + jj] + ao[2] * Wo[8 + jj] + ao[3] * Wo[12 + jj];
        x1[0] += hb0; x1[1] += hb1; x1[2] += hb2; x1[3] += hb3;
        float mean = 0.25f * (x1[0] + x1[1] + x1[2] + x1[3]);
        float var = 0.f;
#pragma unroll
        for (int i = 0; i < 4; ++i) { float d = x1[i] - mean; var += d * d; }
        var *= 0.25f;
        const float rs1 = rsqrtf(var + 1e-5f);
        float h1v[4];
#pragma unroll
        for (int i = 0; i < 4; ++i) h1v[i] = (x1[i] - mean) * rs1 * ln1_g[i] + ln1_b[i];
        float o2[4] = {bf2[0], bf2[1], bf2[2], bf2[3]};
#pragma unroll
        for (int kk = 0; kk < 16; ++kk) {
            float t = bf1[kk];
#pragma unroll
            for (int i = 0; i < 4; ++i) t = fmaf(h1v[i], Wf1[i * 16 + kk], t);
            t = fmaxf(t, 0.0f);
#pragma unroll
            for (int jj = 0; jj < 4; ++jj) o2[jj] = fmaf(t, Wf2[kk * 4 + jj], o2[jj]);
        }
        float x2[4];
#pragma unroll
        for (int i = 0; i < 4; ++i) x2[i] = h1v[i] + o2[i];
        float mean2 = 0.25f * (x2[0] + x2[1] + x2[2] + x2[3]);
        float var2 = 0.f;
#pragma unroll
        for (int i = 0; i < 4; ++i) { float d = x2[i] - mean2; var2 += d * d; }
        var2 *= 0.25f;
        const float rs2 = rsqrtf(var2 + 1e-5f);
        float h2v[4];
#pragma unroll
        for (int i = 0; i < 4; ++i) h2v[i] = (x2[i] - mean2) * rs2 * ln2_g[i] + ln2_b[i];
        float* tp = tr_ws + ((size_t)(b * 256 + s)) * 32;
#pragma unroll
        for (int mm = 0; mm < 32; ++mm)
            tp[mm] = bout[mm] + h2v[0] * Wout[mm] + h2v[1] * Wout[32 + mm]
                   + h2v[2] * Wout[64 + mm] + h2v[3] * Wout[96 + mm];
    }
}

// ============================================================================
// K5: atoms: atom_gen = (emb @ Wa + ba)*valid ; seg_interp gather from x
// grid (130, 32), 128 threads (120 active: d*20+i)
// ============================================================================
__global__ __launch_bounds__(128) void k5_atoms(
    const float* __restrict__ x, const float* __restrict__ tr_ws,
    const int* __restrict__ ends_ws, const int* __restrict__ starts_ws,
    const int* __restrict__ nk_ws,
    const float* __restrict__ Wa, const float* __restrict__ ba,
    float* __restrict__ out)
{
    const int a = blockIdx.x;
    const int b = blockIdx.y;
    const int tid = threadIdx.x;
    __shared__ float emb[32];
    const int e = ends_ws[b * 130 + a];
    const int st = starts_ws[b * 130 + a];
    const int nk = nk_ws[b];
    const float valid = (a <= nk) ? 1.0f : 0.0f;
    const int ec = imin(imax(e - 1, 0), 255);
    if (tid < 32) emb[tid] = tr_ws[((size_t)(b * 256 + ec)) * 32 + tid];
    __syncthreads();
    if (tid < 120) {
        float v = ba[tid];
#pragma unroll
        for (int f = 0; f < 32; ++f) v = fmaf(emb[f], Wa[f * 120 + tid], v);
        out[OFF_ATOM + ((size_t)(b * 130 + a)) * 120 + tid] = v * valid;
        const int d = tid / 20, i = tid % 20;
        const int ilen = (e - st) * 400;
        int idx = st * 400 + (i * ilen) / 20;
        idx = imin(imax(idx, 0), 102399);
        const int si = idx / 400, ti = idx % 400;
        const float px = x[(((size_t)b * 256 + si) * 6 + d) * 400 + ti];
        out[OFF_SEG + ((size_t)(b * 130 + a)) * 120 + tid] = px * valid;
    }
}

// ============================================================================
// K6: imu_gen GEMM: relu(bridge@Wd1+bd1) @ Wd2(64x2400) + bd2
// grid (256 n-tiles of 32, 10 m-tiles of 256), 256 threads, 8x4 micro-tile
// ============================================================================
__global__ __launch_bounds__(256) void k6_imu(
    const float* __restrict__ bridge, const float* __restrict__ Wd1,
    const float* __restrict__ bd1, const float* __restrict__ Wd2,
    const float* __restrict__ bd2, float* __restrict__ out)
{
    __shared__ float hl[64 * 32];     // [f][i]
    const int n0 = blockIdx.x * 32;
    const int mb = blockIdx.y;
    const int tid = threadIdx.x;
    for (int e = tid; e < 2048; e += 256) {
        const int f = e >> 5, i = e & 31;
        const float4 br = *(const float4*)(bridge + (size_t)(n0 + i) * 4);
        const float v = bd1[f] + br.x * Wd1[f] + br.y * Wd1[64 + f]
                      + br.z * Wd1[128 + f] + br.w * Wd1[192 + f];
        hl[f * 32 + i] = fmaxf(v, 0.0f);
    }
    __syncthreads();
    const int gm = tid & 63, gn = tid >> 6;
    const int m0 = mb * 256 + gm * 4;
    if (m0 >= 2400) return;
    float acc[8][4];
#pragma unroll
    for (int r = 0; r < 8; ++r)
#pragma unroll
        for (int c = 0; c < 4; ++c) acc[r][c] = 0.f;
#pragma unroll 4
    for (int f = 0; f < 64; ++f) {
        const float4 w4 = *(const float4*)&Wd2[(size_t)f * 2400 + m0];
        const float4 h0 = *(const float4*)&hl[f * 32 + gn * 8];
        const float4 h1 = *(const float4*)&hl[f * 32 + gn * 8 + 4];
        const float hv[8] = {h0.x, h0.y, h0.z, h0.w, h1.x, h1.y, h1.z, h1.w};
        const float wv[4] = {w4.x, w4.y, w4.z, w4.w};
#pragma unroll
        for (int r = 0; r < 8; ++r)
#pragma unroll
            for (int c = 0; c < 4; ++c) acc[r][c] = fmaf(hv[r], wv[c], acc[r][c]);
    }
    const float4 bb = *(const float4*)&bd2[m0];
#pragma unroll
    for (int r = 0; r < 8; ++r) {
        float4 o;
        o.x = acc[r][0] + bb.x; o.y = acc[r][1] + bb.y;
        o.z = acc[r][2] + bb.z; o.w = acc[r][3] + bb.w;
        *(float4*)&out[OFF_IMU + (size_t)(n0 + gn * 8 + r) * 2400 + m0] = o;
    }
}

// ============================================================================
extern "C" void kernel_launch(void* const* d_in, const int* in_sizes, int n_in,
                              void* d_out, int out_size, void* d_ws, size_t ws_size,
                              hipStream_t stream)
{
    const float* x        = (const float*)d_in[0];
    const float* imu_mask = (const float*)d_in[1];
    const int*   imu_len  = (const int*)  d_in[2];
    const float* conv_w   = (const float*)d_in[3];
    const float* conv_b   = (const float*)d_in[4];
    const float* W_b1     = (const float*)d_in[5];
    const float* b_b1     = (const float*)d_in[6];
    const float* W_fc     = (const float*)d_in[7];
    const float* b_fc     = (const float*)d_in[8];
    const float* Wqkv     = (const float*)d_in[9];
    const float* Wo       = (const float*)d_in[10];
    const float* ln1_g    = (const float*)d_in[11];
    const float* ln1_b    = (const float*)d_in[12];
    const float* Wf1      = (const float*)d_in[13];
    const float* bf1      = (const float*)d_in[14];
    const float* Wf2      = (const float*)d_in[15];
    const float* bf2      = (const float*)d_in[16];
    const float* ln2_g    = (const float*)d_in[17];
    const float* ln2_b    = (const float*)d_in[18];
    const float* Wout     = (const float*)d_in[19];
    const float* bout     = (const float*)d_in[20];
    const float* Wd1      = (const float*)d_in[21];
    const float* bd1      = (const float*)d_in[22];
    const float* Wd2      = (const float*)d_in[23];
    const float* bd2      = (const float*)d_in[24];
    const float* Wa       = (const float*)d_in[25];
    const float* ba       = (const float*)d_in[26];

    float* out = (float*)d_out;
    float* wsf = (float*)d_ws;
    int*   wsi = (int*)d_ws;

    float* bridge = wsf + WS_BRIDGE;
    float* tr_ws  = wsf + WS_TR;
    int* ends   = wsi + WS_ENDS;
    int* starts = wsi + WS_STARTS;
    int* nk     = wsi + WS_NK;

    k1_conv_bridge<<<8192, 128, 0, stream>>>(x, conv_w, conv_b, W_b1, b_b1, bridge);
    k234_seg_attn<<<256, 256, 0, stream>>>(bridge, imu_mask, W_fc, b_fc, imu_len,
                                           out, ends, starts, nk,
                                           Wqkv, Wo, ln1_g, ln1_b, Wf1, bf1,
                                           Wf2, bf2, ln2_g, ln2_b, Wout, bout, tr_ws);
    k5_atoms<<<dim3(130, 32), 128, 0, stream>>>(x, tr_ws, ends, starts, nk, Wa, ba, out);
    k6_imu<<<dim3(256, 10), 256, 0, stream>>>(bridge, Wd1, bd1, Wd2, bd2, out);
}

// Round 16
// 115.644 us; speedup vs baseline: 1.2237x; 1.2237x over previous
//
#include <hip/hip_runtime.h>
#include <math.h>

// ---- output layout ----
#define OFF_IMU  0
#define OFF_ATOM 19660800
#define OFF_SEG  20160000
#define OFF_FC   20659200
#define OFF_FL   20691968

// ---- ws layout (4-byte elements) ----
#define WS_BRIDGE 0        // 32768 floats  (8192 x 4)
#define WS_TR     32768    // 262144 floats (8192 x 32)
#define WS_ENDS   303104   // 4160 ints
#define WS_STARTS 307264   // 4160 ints
#define WS_NK     311424   // 32 ints

static __device__ __forceinline__ int imin(int a, int b) { return a < b ? a : b; }
static __device__ __forceinline__ int imax(int a, int b) { return a > b ? a : b; }

// v_pk_fma_f32: S(.x,.y) += W(.x,.y) * broadcast(X.lo or X.hi)
#define PK_FMA_LO(S, W, X) \
    asm("v_pk_fma_f32 %0, %1, %2, %0 op_sel:[0,0,0] op_sel_hi:[1,0,1]" \
        : "+v"(S) : "v"(W), "v"(X))
#define PK_FMA_HI(S, W, X) \
    asm("v_pk_fma_f32 %0, %1, %2, %0 op_sel:[0,1,0] op_sel_hi:[1,1,1]" \
        : "+v"(S) : "v"(W), "v"(X))

union F4 { float4 q; float2 h[2]; };

// ============================================================================
// K1 (round-13 best, 60.6us measured): conv1d + ReLU + half-mean-pool +
// bridge sigmoid MLP. 4096 blocks x 128 threads; 2 samples/block, one WAVE
// per sample, BARRIER-FREE (all LDS deps intra-wave; lgkmcnt orders same-wave
// ds_write->ds_read). Lane l: oc-pair pr=l&15, half hg=(l>>4)&1, quarter
// q=l>>5; packed fp32 math (v_pk_fma_f32, 2 FMA/instr), rolling window
// (4 groups x 6 chunks), imm-offset ds_read_b128 only.
// [MFMA arc closed: r14 gather=68.9us, r15 im2col=100us (9M bank conflicts);
//  this fp32 structure is the proven k1 plateau.]
// ============================================================================
__global__ __launch_bounds__(128) void k1_conv_bridge(
    const float* __restrict__ x, const float* __restrict__ conv_w,
    const float* __restrict__ conv_b, const float* __restrict__ W_b1,
    const float* __restrict__ b_b1, float* __restrict__ bridge)
{
    __shared__ __align__(16) float xs[2][2424];  // [smp][ic*404 + t]; 400..403 zeroed
    __shared__ float pooledL[2][64];
    const int tid = threadIdx.x;
    const int n0 = blockIdx.x * 2;

    const int wv = tid >> 6;           // wave = sample (0..1)
    const int l  = tid & 63;
    const int pr = l & 15;             // oc pair: 2pr, 2pr+1
    const int hg = (l >> 4) & 1;       // pooling half
    const int q  = l >> 5;             // quarter within half

    float2 W2[18];
    {
        const float* wa = conv_w + (2 * pr) * 18;
        const float* wb = wa + 18;
#pragma unroll
        for (int j = 0; j < 18; ++j) W2[j] = make_float2(wa[j], wb[j]);
    }
    const float2 cb2 = make_float2(conv_b[2 * pr], conv_b[2 * pr + 1]);

    // wave-local staging: wave wv loads sample n0+wv (600 float4, coalesced)
    {
        const float4* xw = (const float4*)(x + (size_t)(n0 + wv) * 2400);
        float* xd = xs[wv];
#pragma unroll
        for (int k = 0; k < 10; ++k) {
            const int i = l + k * 64;              // k=9: only l<24 active
            if (k < 9 || i < 600) {
                const float4 v = xw[i];
                const int ic = i / 100;
                const int t4 = (i - ic * 100) * 4;
                *(float4*)&xd[ic * 404 + t4] = v;
            }
        }
        if (l < 24) xd[(l >> 2) * 404 + 400 + (l & 3)] = 0.0f;  // zero pads
        // no barrier: same-wave LDS coherence via lgkmcnt
    }

    const float* rb = &xs[wv][hg * 200 + q * 100];
    float2 accMain = make_float2(0.0f, 0.0f);
    float2 extra   = make_float2(0.0f, 0.0f);

    float2 c01[6], c23[6];             // rolling window pairs
#pragma unroll
    for (int ic = 0; ic < 6; ++ic) {
        const F4 f = *(const F4*)(rb + ic * 404);
        c01[ic] = f.h[0]; c23[ic] = f.h[1];
    }

    for (int g = 0; g < 4; ++g) {
#pragma unroll
        for (int u = 0; u < 6; ++u) {
            float2 S0 = cb2, S1 = cb2, S2 = cb2, S3 = cb2;
#pragma unroll
            for (int ic = 0; ic < 6; ++ic) {
                const F4 nf = *(const F4*)(rb + ic * 404 + (u + 1) * 4);
                const float2 n01 = nf.h[0];
                const float2 w0 = W2[ic*3+0], w1 = W2[ic*3+1], w2 = W2[ic*3+2];
                PK_FMA_LO(S0, w0, c01[ic]); PK_FMA_HI(S0, w1, c01[ic]); PK_FMA_LO(S0, w2, c23[ic]);
                PK_FMA_HI(S1, w0, c01[ic]); PK_FMA_LO(S1, w1, c23[ic]); PK_FMA_HI(S1, w2, c23[ic]);
                PK_FMA_LO(S2, w0, c23[ic]); PK_FMA_HI(S2, w1, c23[ic]); PK_FMA_LO(S2, w2, n01);
                PK_FMA_HI(S3, w0, c23[ic]); PK_FMA_LO(S3, w1, n01);     PK_FMA_HI(S3, w2, n01);
                c01[ic] = n01; c23[ic] = nf.h[1];
            }
            accMain.x += fmaxf(S0.x,0.f)+fmaxf(S1.x,0.f)+fmaxf(S2.x,0.f)+fmaxf(S3.x,0.f);
            accMain.y += fmaxf(S0.y,0.f)+fmaxf(S1.y,0.f)+fmaxf(S2.y,0.f)+fmaxf(S3.y,0.f);
        }
        rb += 24;
    }

    // tail chunk 24 (t = qbase+96..99); pads keep math finite
    {
        float2 S0 = cb2, S1 = cb2, S2 = cb2, S3 = cb2;
#pragma unroll
        for (int ic = 0; ic < 6; ++ic) {
            const F4 nf = *(const F4*)(rb + ic * 404 + 4);
            const float2 n01 = nf.h[0];
            const float2 w0 = W2[ic*3+0], w1 = W2[ic*3+1], w2 = W2[ic*3+2];
            PK_FMA_LO(S0, w0, c01[ic]); PK_FMA_HI(S0, w1, c01[ic]); PK_FMA_LO(S0, w2, c23[ic]);
            PK_FMA_HI(S1, w0, c01[ic]); PK_FMA_LO(S1, w1, c23[ic]); PK_FMA_HI(S1, w2, c23[ic]);
            PK_FMA_LO(S2, w0, c23[ic]); PK_FMA_HI(S2, w1, c23[ic]); PK_FMA_LO(S2, w2, n01);
            PK_FMA_HI(S3, w0, c23[ic]); PK_FMA_LO(S3, w1, n01);     PK_FMA_HI(S3, w2, n01);
        }
        const float r0x = fmaxf(S0.x,0.f), r0y = fmaxf(S0.y,0.f);
        const float r1x = fmaxf(S1.x,0.f), r1y = fmaxf(S1.y,0.f);
        const float r2x = fmaxf(S2.x,0.f), r2y = fmaxf(S2.y,0.f);
        const float r3x = fmaxf(S3.x,0.f), r3y = fmaxf(S3.y,0.f);
        if (q == 0) {
            accMain.x += r0x + r1x + r2x + r3x;
            accMain.y += r0y + r1y + r2y + r3y;
        } else if (hg == 0) {
            accMain.x += r0x + r1x + r2x;  extra.x = r3x;
            accMain.y += r0y + r1y + r2y;  extra.y = r3y;
        } else {
            accMain.x += r0x + r1x;
            accMain.y += r0y + r1y;
        }
    }

    // merge quarters (xor32) then route the t=199 extra (q1,hg0)->(q1,hg1)
    float2 tot;
    tot.x = accMain.x + __shfl_xor(accMain.x, 32);
    tot.y = accMain.y + __shfl_xor(accMain.y, 32);
    const float exx = __shfl_xor(extra.x, 16);
    const float exy = __shfl_xor(extra.y, 16);
    if (hg) { tot.x += exx; tot.y += exy; }
    if (q) {
        pooledL[wv][(2 * pr + 0) * 2 + hg] = tot.x * (1.0f / 199.0f);
        pooledL[wv][(2 * pr + 1) * 2 + hg] = tot.y * (1.0f / 199.0f);
    }
    // no barrier: pooledL[wv] is read only by wave wv below

    // bridge MLP: sample = own wave, feature f = lane
    {
        const float v = pooledL[wv][l];
        const float4 wb = *(const float4*)(W_b1 + l * 4);
        float p0 = v * wb.x, p1 = v * wb.y, p2 = v * wb.z, p3 = v * wb.w;
#pragma unroll
        for (int off = 1; off < 64; off <<= 1) {
            p0 += __shfl_xor(p0, off, 64);
            p1 += __shfl_xor(p1, off, 64);
            p2 += __shfl_xor(p2, off, 64);
            p3 += __shfl_xor(p3, off, 64);
        }
        if (l == 0) {
            float* bp = bridge + (size_t)(n0 + wv) * 4;
            bp[0] = 1.0f / (1.0f + __expf(-(p0 + b_b1[0])));
            bp[1] = 1.0f / (1.0f + __expf(-(p1 + b_b1[1])));
            bp[2] = 1.0f / (1.0f + __expf(-(p2 + b_b1[2])));
            bp[3] = 1.0f / (1.0f + __expf(-(p3 + b_b1[3])));
        }
    }
}

// ============================================================================
// K234: forcast+floss (out) + segmentation (local) + attention + transformer.
// grid 256 = (b, 32-query chunk), 256 threads. Each block recomputes the
// per-b segmentation locally; ends/starts/nk written redundantly (same values).
// hb[b,s] = bridge[s*32 + b] (scrambled). exp() select-guarded.
// ============================================================================
__global__ __launch_bounds__(256) void k234_seg_attn(
    const float* __restrict__ bridge, const float* __restrict__ imu_mask,
    const float* __restrict__ W_fc, const float* __restrict__ b_fc,
    const int* __restrict__ imu_len, float* __restrict__ out,
    int* __restrict__ ends_ws, int* __restrict__ starts_ws, int* __restrict__ nk_ws,
    const float* __restrict__ Wqkv, const float* __restrict__ Wo,
    const float* __restrict__ ln1_g, const float* __restrict__ ln1_b,
    const float* __restrict__ Wf1, const float* __restrict__ bf1,
    const float* __restrict__ Wf2, const float* __restrict__ bf2,
    const float* __restrict__ ln2_g, const float* __restrict__ ln2_b,
    const float* __restrict__ Wout, const float* __restrict__ bout,
    float* __restrict__ tr_ws)
{
    const int b = blockIdx.x >> 3;
    const int chunk = blockIdx.x & 7;
    const int tid = threadIdx.x;
    __shared__ float kv[256][8];
    __shared__ int sid[256];
    __shared__ float part[32][8][8];
    __shared__ float fl[256];
    __shared__ float sel[256];
    __shared__ float sp[256];
    __shared__ int pk[256];
    __shared__ int sc[2][256];
    __shared__ int kpl[256];

    // ---- stage K/V for all 256 keys (independent of segmentation) ----
    {
        const float4 h = *(const float4*)(bridge + (size_t)(tid * 32 + b) * 4);
#pragma unroll
        for (int e = 0; e < 4; ++e) {
            kv[tid][e]     = h.x * Wqkv[16 + e] + h.y * Wqkv[20 + e] + h.z * Wqkv[24 + e] + h.w * Wqkv[28 + e];
            kv[tid][4 + e] = h.x * Wqkv[32 + e] + h.y * Wqkv[36 + e] + h.z * Wqkv[40 + e] + h.w * Wqkv[44 + e];
        }
    }

    // ---- forcast + floss (n = b*256 + tid) ----
    {
        const int n = b * 256 + tid;
        float sh[4], cur[4];
#pragma unroll
        for (int j = 0; j < 4; ++j) {
            sh[j] = (tid == 0) ? 0.0f : bridge[(n - 1) * 4 + j];
            cur[j] = bridge[n * 4 + j];
        }
        const float fm = ((tid == 0) ? 0.0f : 1.0f) * imu_mask[n];
        float flv = 0.0f;
#pragma unroll
        for (int j = 0; j < 4; ++j) {
            float f = b_fc[j];
#pragma unroll
            for (int i = 0; i < 4; ++i) f = fmaf(sh[i], W_fc[i * 4 + j], f);
            out[OFF_FC + n * 4 + j] = f;
            const float d = (f - cur[j]) * fm;
            flv = fmaf(d, d, flv);
        }
        flv *= 0.25f;
        const bool lm = (tid >= 2) && (tid < 254);
        flv = (flv > 0.001f && lm) ? flv : 0.0f;
        out[OFF_FL + n] = flv;
        fl[tid] = flv;
        sp[tid] = 0.0f;
    }
    __syncthreads();

    // ---- segmentation (local) ----
    if (tid < 64) {                       // sel: windows of 4, first-max
        const int base = tid * 4;
        float m = fl[base]; int idx = 0;
#pragma unroll
        for (int i = 1; i < 4; ++i) { float v = fl[base + i]; if (v > m) { m = v; idx = i; } }
#pragma unroll
        for (int i = 0; i < 4; ++i) sel[base + i] = (i == idx) ? m : 0.0f;
    }
    __syncthreads();
    if (tid < 63) {                       // sel2 on sel[2:254)
        const int base = 2 + tid * 4;
        float m = sel[base]; int idx = 0;
#pragma unroll
        for (int i = 1; i < 4; ++i) { float v = sel[base + i]; if (v > m) { m = v; idx = i; } }
        sp[base + idx] = (m > 0.0f) ? 1.0f : 0.0f;
    }
    __syncthreads();
    int last = (int)rintf((float)imu_len[b] * (1.0f / 256.0f));  // half-even
    last = imin(imax(last, 2), 256);
    const int point = ((sp[tid] > 0.0f) && (tid < last)) ? 1 : 0;
    pk[tid] = point;
    __syncthreads();
    const int pnext = (tid < 255) ? pk[tid + 1] : 0;
    const int bnd = pnext | ((tid + 1 == last) ? 1 : 0);
    const int kept = (point && !bnd) ? 1 : 0;
    __syncthreads();
    sc[0][tid] = kept;
    __syncthreads();
    int src = 0;                          // Hillis-Steele inclusive scan
    for (int off = 1; off < 256; off <<= 1) {
        const int v = sc[src][tid] + ((tid >= off) ? sc[src][tid - off] : 0);
        sc[src ^ 1][tid] = v;
        __syncthreads();
        src ^= 1;
    }
    const int myid = sc[src][tid];
    sid[tid] = myid;
    const int nk = sc[src][255];
    if (kept) kpl[myid - 1] = tid;
    __syncthreads();
    if (tid < 130) {                      // redundant across the 8 b-blocks
        ends_ws[b * 130 + tid] = (tid < nk) ? kpl[tid] : last;
        starts_ws[b * 130 + tid] = (tid == 0) ? 0 : ((tid - 1 < nk) ? kpl[tid - 1] : last);
    }
    if (tid == 0) nk_ws[b] = nk;

    // ---- attention ----
    const int lq = tid & 31;
    const int jg = tid >> 5;
    const int sq = chunk * 32 + lq;
    {
        const float4 h = *(const float4*)(bridge + (size_t)(sq * 32 + b) * 4);
        float qv[4];
#pragma unroll
        for (int e = 0; e < 4; ++e)
            qv[e] = h.x * Wqkv[e] + h.y * Wqkv[4 + e] + h.z * Wqkv[8 + e] + h.w * Wqkv[12 + e];
        const bool vs = sq < last;
        const int ms = sid[sq];
        const float isq = 0.70710678118654752f;
        float m0 = -1e30f, l0 = 0.f, a00 = 0.f, a01 = 0.f;
        float m1 = -1e30f, l1 = 0.f, a10 = 0.f, a11 = 0.f;
#pragma unroll 4
        for (int jj = 0; jj < 32; ++jj) {
            const int j = jg * 32 + jj;
            const bool allowed = (j == sq) || (vs && (j < last) && (sid[j] == ms));
            const float sc0 = (qv[0] * kv[j][0] + qv[1] * kv[j][1]) * isq;
            const float sc1 = (qv[2] * kv[j][2] + qv[3] * kv[j][3]) * isq;
            {
                const float mn = allowed ? fmaxf(m0, sc0) : m0;
                const float c = __expf(m0 - mn);                      // arg <= 0 always
                const float e = allowed ? __expf(sc0 - mn) : 0.0f;    // select: no inf*0
                l0 = l0 * c + e; a00 = a00 * c + e * kv[j][4]; a01 = a01 * c + e * kv[j][5]; m0 = mn;
            }
            {
                const float mn = allowed ? fmaxf(m1, sc1) : m1;
                const float c = __expf(m1 - mn);
                const float e = allowed ? __expf(sc1 - mn) : 0.0f;
                l1 = l1 * c + e; a10 = a10 * c + e * kv[j][6]; a11 = a11 * c + e * kv[j][7]; m1 = mn;
            }
        }
        float* pp = part[lq][jg];
        pp[0] = m0; pp[1] = l0; pp[2] = a00; pp[3] = a01;
        pp[4] = m1; pp[5] = l1; pp[6] = a10; pp[7] = a11;
    }
    __syncthreads();
    if (tid < 32) {
        const int s = chunk * 32 + tid;
        float M0 = -1e30f, L0 = 0.f, A00 = 0.f, A01 = 0.f;
        float M1 = -1e30f, L1 = 0.f, A10 = 0.f, A11 = 0.f;
#pragma unroll
        for (int p = 0; p < 8; ++p) {
            const float* pp = part[tid][p];
            {
                const float mn = fmaxf(M0, pp[0]);
                const float c0 = __expf(M0 - mn), c1 = __expf(pp[0] - mn);   // args <= 0
                L0 = L0 * c0 + pp[1] * c1; A00 = A00 * c0 + pp[2] * c1; A01 = A01 * c0 + pp[3] * c1; M0 = mn;
            }
            {
                const float mn = fmaxf(M1, pp[4]);
                const float c0 = __expf(M1 - mn), c1 = __expf(pp[4] - mn);
                L1 = L1 * c0 + pp[5] * c1; A10 = A10 * c0 + pp[6] * c1; A11 = A11 * c0 + pp[7] * c1; M1 = mn;
            }
        }
        const float4 h = *(const float4*)(bridge + (size_t)(s * 32 + b) * 4);
        const float hb0 = h.x, hb1 = h.y, hb2 = h.z, hb3 = h.w;
        float ao[4] = {A00 / L0, A01 / L0, A10 / L1, A11 / L1};
        float x1[4];
#pragma unroll
        for (int jj = 0; jj < 4; ++jj)
            x1[jj] = ao[0] * Wo[jj] + ao[1] * Wo[4 + jj] + ao[2] * Wo[8 + jj] + ao[3] * Wo[12 + jj];
        x1[0] += hb0; x1[1] += hb1; x1[2] += hb2; x1[3] += hb3;
        float mean = 0.25f * (x1[0] + x1[1] + x1[2] + x1[3]);
        float var = 0.f;
#pragma unroll
        for (int i = 0; i < 4; ++i) { float d = x1[i] - mean; var += d * d; }
        var *= 0.25f;
        const float rs1 = rsqrtf(var + 1e-5f);
        float h1v[4];
#pragma unroll
        for (int i = 0; i < 4; ++i) h1v[i] = (x1[i] - mean) * rs1 * ln1_g[i] + ln1_b[i];
        float o2[4] = {bf2[0], bf2[1], bf2[2], bf2[3]};
#pragma unroll
        for (int kk = 0; kk < 16; ++kk) {
            float t = bf1[kk];
#pragma unroll
            for (int i = 0; i < 4; ++i) t = fmaf(h1v[i], Wf1[i * 16 + kk], t);
            t = fmaxf(t, 0.0f);
#pragma unroll
            for (int jj = 0; jj < 4; ++jj) o2[jj] = fmaf(t, Wf2[kk * 4 + jj], o2[jj]);
        }
        float x2[4];
#pragma unroll
        for (int i = 0; i < 4; ++i) x2[i] = h1v[i] + o2[i];
        float mean2 = 0.25f * (x2[0] + x2[1] + x2[2] + x2[3]);
        float var2 = 0.f;
#pragma unroll
        for (int i = 0; i < 4; ++i) { float d = x2[i] - mean2; var2 += d * d; }
        var2 *= 0.25f;
        const float rs2 = rsqrtf(var2 + 1e-5f);
        float h2v[4];
#pragma unroll
        for (int i = 0; i < 4; ++i) h2v[i] = (x2[i] - mean2) * rs2 * ln2_g[i] + ln2_b[i];
        float* tp = tr_ws + ((size_t)(b * 256 + s)) * 32;
#pragma unroll
        for (int mm = 0; mm < 32; ++mm)
            tp[mm] = bout[mm] + h2v[0] * Wout[mm] + h2v[1] * Wout[32 + mm]
                   + h2v[2] * Wout[64 + mm] + h2v[3] * Wout[96 + mm];
    }
}

// ============================================================================
// K5: atoms: atom_gen = (emb @ Wa + ba)*valid ; seg_interp gather from x
// grid (130, 32), 128 threads (120 active: d*20+i)
// ============================================================================
__global__ __launch_bounds__(128) void k5_atoms(
    const float* __restrict__ x, const float* __restrict__ tr_ws,
    const int* __restrict__ ends_ws, const int* __restrict__ starts_ws,
    const int* __restrict__ nk_ws,
    const float* __restrict__ Wa, const float* __restrict__ ba,
    float* __restrict__ out)
{
    const int a = blockIdx.x;
    const int b = blockIdx.y;
    const int tid = threadIdx.x;
    __shared__ float emb[32];
    const int e = ends_ws[b * 130 + a];
    const int st = starts_ws[b * 130 + a];
    const int nk = nk_ws[b];
    const float valid = (a <= nk) ? 1.0f : 0.0f;
    const int ec = imin(imax(e - 1, 0), 255);
    if (tid < 32) emb[tid] = tr_ws[((size_t)(b * 256 + ec)) * 32 + tid];
    __syncthreads();
    if (tid < 120) {
        float v = ba[tid];
#pragma unroll
        for (int f = 0; f < 32; ++f) v = fmaf(emb[f], Wa[f * 120 + tid], v);
        out[OFF_ATOM + ((size_t)(b * 130 + a)) * 120 + tid] = v * valid;
        const int d = tid / 20, i = tid % 20;
        const int ilen = (e - st) * 400;
        int idx = st * 400 + (i * ilen) / 20;
        idx = imin(imax(idx, 0), 102399);
        const int si = idx / 400, ti = idx % 400;
        const float px = x[(((size_t)b * 256 + si) * 6 + d) * 400 + ti];
        out[OFF_SEG + ((size_t)(b * 130 + a)) * 120 + tid] = px * valid;
    }
}

// ============================================================================
// K6: imu_gen GEMM: relu(bridge@Wd1+bd1) @ Wd2(64x2400) + bd2
// grid (256 n-tiles of 32, 10 m-tiles of 256), 256 threads, 8x4 micro-tile
// ============================================================================
__global__ __launch_bounds__(256) void k6_imu(
    const float* __restrict__ bridge, const float* __restrict__ Wd1,
    const float* __restrict__ bd1, const float* __restrict__ Wd2,
    const float* __restrict__ bd2, float* __restrict__ out)
{
    __shared__ float hl[64 * 32];     // [f][i]
    const int n0 = blockIdx.x * 32;
    const int mb = blockIdx.y;
    const int tid = threadIdx.x;
    for (int e = tid; e < 2048; e += 256) {
        const int f = e >> 5, i = e & 31;
        const float4 br = *(const float4*)(bridge + (size_t)(n0 + i) * 4);
        const float v = bd1[f] + br.x * Wd1[f] + br.y * Wd1[64 + f]
                      + br.z * Wd1[128 + f] + br.w * Wd1[192 + f];
        hl[f * 32 + i] = fmaxf(v, 0.0f);
    }
    __syncthreads();
    const int gm = tid & 63, gn = tid >> 6;
    const int m0 = mb * 256 + gm * 4;
    if (m0 >= 2400) return;
    float acc[8][4];
#pragma unroll
    for (int r = 0; r < 8; ++r)
#pragma unroll
        for (int c = 0; c < 4; ++c) acc[r][c] = 0.f;
#pragma unroll 4
    for (int f = 0; f < 64; ++f) {
        const float4 w4 = *(const float4*)&Wd2[(size_t)f * 2400 + m0];
        const float4 h0 = *(const float4*)&hl[f * 32 + gn * 8];
        const float4 h1 = *(const float4*)&hl[f * 32 + gn * 8 + 4];
        const float hv[8] = {h0.x, h0.y, h0.z, h0.w, h1.x, h1.y, h1.z, h1.w};
        const float wv[4] = {w4.x, w4.y, w4.z, w4.w};
#pragma unroll
        for (int r = 0; r < 8; ++r)
#pragma unroll
            for (int c = 0; c < 4; ++c) acc[r][c] = fmaf(hv[r], wv[c], acc[r][c]);
    }
    const float4 bb = *(const float4*)&bd2[m0];
#pragma unroll
    for (int r = 0; r < 8; ++r) {
        float4 o;
        o.x = acc[r][0] + bb.x; o.y = acc[r][1] + bb.y;
        o.z = acc[r][2] + bb.z; o.w = acc[r][3] + bb.w;
        *(float4*)&out[OFF_IMU + (size_t)(n0 + gn * 8 + r) * 2400 + m0] = o;
    }
}

// ============================================================================
extern "C" void kernel_launch(void* const* d_in, const int* in_sizes, int n_in,
                              void* d_out, int out_size, void* d_ws, size_t ws_size,
                              hipStream_t stream)
{
    const float* x        = (const float*)d_in[0];
    const float* imu_mask = (const float*)d_in[1];
    const int*   imu_len  = (const int*)  d_in[2];
    const float* conv_w   = (const float*)d_in[3];
    const float* conv_b   = (const float*)d_in[4];
    const float* W_b1     = (const float*)d_in[5];
    const float* b_b1     = (const float*)d_in[6];
    const float* W_fc     = (const float*)d_in[7];
    const float* b_fc     = (const float*)d_in[8];
    const float* Wqkv     = (const float*)d_in[9];
    const float* Wo       = (const float*)d_in[10];
    const float* ln1_g    = (const float*)d_in[11];
    const float* ln1_b    = (const float*)d_in[12];
    const float* Wf1      = (const float*)d_in[13];
    const float* bf1      = (const float*)d_in[14];
    const float* Wf2      = (const float*)d_in[15];
    const float* bf2      = (const float*)d_in[16];
    const float* ln2_g    = (const float*)d_in[17];
    const float* ln2_b    = (const float*)d_in[18];
    const float* Wout     = (const float*)d_in[19];
    const float* bout     = (const float*)d_in[20];
    const float* Wd1      = (const float*)d_in[21];
    const float* bd1      = (const float*)d_in[22];
    const float* Wd2      = (const float*)d_in[23];
    const float* bd2      = (const float*)d_in[24];
    const float* Wa       = (const float*)d_in[25];
    const float* ba       = (const float*)d_in[26];

    float* out = (float*)d_out;
    float* wsf = (float*)d_ws;
    int*   wsi = (int*)d_ws;

    float* bridge = wsf + WS_BRIDGE;
    float* tr_ws  = wsf + WS_TR;
    int* ends   = wsi + WS_ENDS;
    int* starts = wsi + WS_STARTS;
    int* nk     = wsi + WS_NK;

    k1_conv_bridge<<<4096, 128, 0, stream>>>(x, conv_w, conv_b, W_b1, b_b1, bridge);
    k234_seg_attn<<<256, 256, 0, stream>>>(bridge, imu_mask, W_fc, b_fc, imu_len,
                                           out, ends, starts, nk,
                                           Wqkv, Wo, ln1_g, ln1_b, Wf1, bf1,
                                           Wf2, bf2, ln2_g, ln2_b, Wout, bout, tr_ws);
    k5_atoms<<<dim3(130, 32), 128, 0, stream>>>(x, tr_ws, ends, starts, nk, Wa, ba, out);
    k6_imu<<<dim3(256, 10), 256, 0, stream>>>(bridge, Wd1, bd1, Wd2, bd2, out);
}

// Round 17
// 104.156 us; speedup vs baseline: 1.3587x; 1.1103x over previous
//
#include <hip/hip_runtime.h>
#include <math.h>

// ---- output layout ----
#define OFF_IMU  0
#define OFF_ATOM 19660800
#define OFF_SEG  20160000
#define OFF_FC   20659200
#define OFF_FL   20691968

// ---- ws layout (4-byte elements) ----
#define WS_BRIDGE 0        // 32768 floats  (8192 x 4)
#define WS_TR     32768    // 262144 floats (8192 x 32)
#define WS_ENDS   303104   // 4160 ints
#define WS_STARTS 307264   // 4160 ints
#define WS_NK     311424   // 32 ints

static __device__ __forceinline__ int imin(int a, int b) { return a < b ? a : b; }
static __device__ __forceinline__ int imax(int a, int b) { return a > b ? a : b; }

// v_pk_fma_f32: S(.x,.y) += W(.x,.y) * broadcast(X.lo or X.hi)
#define PK_FMA_LO(S, W, X) \
    asm("v_pk_fma_f32 %0, %1, %2, %0 op_sel:[0,0,0] op_sel_hi:[1,0,1]" \
        : "+v"(S) : "v"(W), "v"(X))
#define PK_FMA_HI(S, W, X) \
    asm("v_pk_fma_f32 %0, %1, %2, %0 op_sel:[0,1,0] op_sel_hi:[1,1,1]" \
        : "+v"(S) : "v"(W), "v"(X))

union F4 { float4 q; float2 h[2]; };

// ============================================================================
// K1 (plateau, 60.6us measured): conv1d + ReLU + half-mean-pool + bridge MLP.
// 4096 blocks x 128 threads; 2 samples/block, one WAVE per sample,
// BARRIER-FREE; packed fp32 math, rolling window, imm-offset ds_read_b128.
// ============================================================================
__global__ __launch_bounds__(128) void k1_conv_bridge(
    const float* __restrict__ x, const float* __restrict__ conv_w,
    const float* __restrict__ conv_b, const float* __restrict__ W_b1,
    const float* __restrict__ b_b1, float* __restrict__ bridge)
{
    __shared__ __align__(16) float xs[2][2424];  // [smp][ic*404 + t]; 400..403 zeroed
    __shared__ float pooledL[2][64];
    const int tid = threadIdx.x;
    const int n0 = blockIdx.x * 2;

    const int wv = tid >> 6;           // wave = sample (0..1)
    const int l  = tid & 63;
    const int pr = l & 15;             // oc pair: 2pr, 2pr+1
    const int hg = (l >> 4) & 1;       // pooling half
    const int q  = l >> 5;             // quarter within half

    float2 W2[18];
    {
        const float* wa = conv_w + (2 * pr) * 18;
        const float* wb = wa + 18;
#pragma unroll
        for (int j = 0; j < 18; ++j) W2[j] = make_float2(wa[j], wb[j]);
    }
    const float2 cb2 = make_float2(conv_b[2 * pr], conv_b[2 * pr + 1]);

    // wave-local staging: wave wv loads sample n0+wv (600 float4, coalesced)
    {
        const float4* xw = (const float4*)(x + (size_t)(n0 + wv) * 2400);
        float* xd = xs[wv];
#pragma unroll
        for (int k = 0; k < 10; ++k) {
            const int i = l + k * 64;              // k=9: only l<24 active
            if (k < 9 || i < 600) {
                const float4 v = xw[i];
                const int ic = i / 100;
                const int t4 = (i - ic * 100) * 4;
                *(float4*)&xd[ic * 404 + t4] = v;
            }
        }
        if (l < 24) xd[(l >> 2) * 404 + 400 + (l & 3)] = 0.0f;  // zero pads
        // no barrier: same-wave LDS coherence via lgkmcnt
    }

    const float* rb = &xs[wv][hg * 200 + q * 100];
    float2 accMain = make_float2(0.0f, 0.0f);
    float2 extra   = make_float2(0.0f, 0.0f);

    float2 c01[6], c23[6];             // rolling window pairs
#pragma unroll
    for (int ic = 0; ic < 6; ++ic) {
        const F4 f = *(const F4*)(rb + ic * 404);
        c01[ic] = f.h[0]; c23[ic] = f.h[1];
    }

    for (int g = 0; g < 4; ++g) {
#pragma unroll
        for (int u = 0; u < 6; ++u) {
            float2 S0 = cb2, S1 = cb2, S2 = cb2, S3 = cb2;
#pragma unroll
            for (int ic = 0; ic < 6; ++ic) {
                const F4 nf = *(const F4*)(rb + ic * 404 + (u + 1) * 4);
                const float2 n01 = nf.h[0];
                const float2 w0 = W2[ic*3+0], w1 = W2[ic*3+1], w2 = W2[ic*3+2];
                PK_FMA_LO(S0, w0, c01[ic]); PK_FMA_HI(S0, w1, c01[ic]); PK_FMA_LO(S0, w2, c23[ic]);
                PK_FMA_HI(S1, w0, c01[ic]); PK_FMA_LO(S1, w1, c23[ic]); PK_FMA_HI(S1, w2, c23[ic]);
                PK_FMA_LO(S2, w0, c23[ic]); PK_FMA_HI(S2, w1, c23[ic]); PK_FMA_LO(S2, w2, n01);
                PK_FMA_HI(S3, w0, c23[ic]); PK_FMA_LO(S3, w1, n01);     PK_FMA_HI(S3, w2, n01);
                c01[ic] = n01; c23[ic] = nf.h[1];
            }
            accMain.x += fmaxf(S0.x,0.f)+fmaxf(S1.x,0.f)+fmaxf(S2.x,0.f)+fmaxf(S3.x,0.f);
            accMain.y += fmaxf(S0.y,0.f)+fmaxf(S1.y,0.f)+fmaxf(S2.y,0.f)+fmaxf(S3.y,0.f);
        }
        rb += 24;
    }

    // tail chunk 24 (t = qbase+96..99); pads keep math finite
    {
        float2 S0 = cb2, S1 = cb2, S2 = cb2, S3 = cb2;
#pragma unroll
        for (int ic = 0; ic < 6; ++ic) {
            const F4 nf = *(const F4*)(rb + ic * 404 + 4);
            const float2 n01 = nf.h[0];
            const float2 w0 = W2[ic*3+0], w1 = W2[ic*3+1], w2 = W2[ic*3+2];
            PK_FMA_LO(S0, w0, c01[ic]); PK_FMA_HI(S0, w1, c01[ic]); PK_FMA_LO(S0, w2, c23[ic]);
            PK_FMA_HI(S1, w0, c01[ic]); PK_FMA_LO(S1, w1, c23[ic]); PK_FMA_HI(S1, w2, c23[ic]);
            PK_FMA_LO(S2, w0, c23[ic]); PK_FMA_HI(S2, w1, c23[ic]); PK_FMA_LO(S2, w2, n01);
            PK_FMA_HI(S3, w0, c23[ic]); PK_FMA_LO(S3, w1, n01);     PK_FMA_HI(S3, w2, n01);
        }
        const float r0x = fmaxf(S0.x,0.f), r0y = fmaxf(S0.y,0.f);
        const float r1x = fmaxf(S1.x,0.f), r1y = fmaxf(S1.y,0.f);
        const float r2x = fmaxf(S2.x,0.f), r2y = fmaxf(S2.y,0.f);
        const float r3x = fmaxf(S3.x,0.f), r3y = fmaxf(S3.y,0.f);
        if (q == 0) {
            accMain.x += r0x + r1x + r2x + r3x;
            accMain.y += r0y + r1y + r2y + r3y;
        } else if (hg == 0) {
            accMain.x += r0x + r1x + r2x;  extra.x = r3x;
            accMain.y += r0y + r1y + r2y;  extra.y = r3y;
        } else {
            accMain.x += r0x + r1x;
            accMain.y += r0y + r1y;
        }
    }

    // merge quarters (xor32) then route the t=199 extra (q1,hg0)->(q1,hg1)
    float2 tot;
    tot.x = accMain.x + __shfl_xor(accMain.x, 32);
    tot.y = accMain.y + __shfl_xor(accMain.y, 32);
    const float exx = __shfl_xor(extra.x, 16);
    const float exy = __shfl_xor(extra.y, 16);
    if (hg) { tot.x += exx; tot.y += exy; }
    if (q) {
        pooledL[wv][(2 * pr + 0) * 2 + hg] = tot.x * (1.0f / 199.0f);
        pooledL[wv][(2 * pr + 1) * 2 + hg] = tot.y * (1.0f / 199.0f);
    }
    // no barrier: pooledL[wv] is read only by wave wv below

    // bridge MLP: sample = own wave, feature f = lane
    {
        const float v = pooledL[wv][l];
        const float4 wb = *(const float4*)(W_b1 + l * 4);
        float p0 = v * wb.x, p1 = v * wb.y, p2 = v * wb.z, p3 = v * wb.w;
#pragma unroll
        for (int off = 1; off < 64; off <<= 1) {
            p0 += __shfl_xor(p0, off, 64);
            p1 += __shfl_xor(p1, off, 64);
            p2 += __shfl_xor(p2, off, 64);
            p3 += __shfl_xor(p3, off, 64);
        }
        if (l == 0) {
            float* bp = bridge + (size_t)(n0 + wv) * 4;
            bp[0] = 1.0f / (1.0f + __expf(-(p0 + b_b1[0])));
            bp[1] = 1.0f / (1.0f + __expf(-(p1 + b_b1[1])));
            bp[2] = 1.0f / (1.0f + __expf(-(p2 + b_b1[2])));
            bp[3] = 1.0f / (1.0f + __expf(-(p3 + b_b1[3])));
        }
    }
}

// ---- shared-memory unions for the fused kernel ----
struct S234 {
    float kv[256][8];
    int   sid[256];
    float part[32][8][8];
    float fl[256];
    float sel[256];
    float sp[256];
    int   pk[256];
    int   sc[2][256];
    int   kpl[256];
};
struct S6 { float hl[64 * 32]; };

// ============================================================================
// K2346: union kernel. Blocks 0..255: forcast+floss+segmentation+attention+
// transformer (k234 body, 1 block/CU, barrier-heavy). Blocks 256..2815: the
// independent imu_gen GEMM (k6 body) — fills the idle wave slots and streams
// its HBM writes underneath k234's barrier stalls. Both bodies verbatim;
// LDS is a union (24.6 KB). k234 blocks at low blockIdx dispatch first.
// ============================================================================
__global__ __launch_bounds__(256) void k2346_attn_imu(
    const float* __restrict__ bridge, const float* __restrict__ imu_mask,
    const float* __restrict__ W_fc, const float* __restrict__ b_fc,
    const int* __restrict__ imu_len, float* __restrict__ out,
    int* __restrict__ ends_ws, int* __restrict__ starts_ws, int* __restrict__ nk_ws,
    const float* __restrict__ Wqkv, const float* __restrict__ Wo,
    const float* __restrict__ ln1_g, const float* __restrict__ ln1_b,
    const float* __restrict__ Wf1, const float* __restrict__ bf1,
    const float* __restrict__ Wf2, const float* __restrict__ bf2,
    const float* __restrict__ ln2_g, const float* __restrict__ ln2_b,
    const float* __restrict__ Wout, const float* __restrict__ bout,
    float* __restrict__ tr_ws,
    const float* __restrict__ Wd1, const float* __restrict__ bd1,
    const float* __restrict__ Wd2, const float* __restrict__ bd2)
{
    __shared__ __align__(16) char smem[sizeof(S234)];
    const int tid = threadIdx.x;

    if (blockIdx.x >= 256) {
        // ------------------------- k6: imu_gen GEMM -------------------------
        S6& sm = *(S6*)smem;
        const int bx = blockIdx.x - 256;
        const int n0 = (bx & 255) * 32;
        const int mb = bx >> 8;
        for (int e = tid; e < 2048; e += 256) {
            const int f = e >> 5, i = e & 31;
            const float4 br = *(const float4*)(bridge + (size_t)(n0 + i) * 4);
            const float v = bd1[f] + br.x * Wd1[f] + br.y * Wd1[64 + f]
                          + br.z * Wd1[128 + f] + br.w * Wd1[192 + f];
            sm.hl[f * 32 + i] = fmaxf(v, 0.0f);
        }
        __syncthreads();
        const int gm = tid & 63, gn = tid >> 6;
        const int m0 = mb * 256 + gm * 4;
        if (m0 >= 2400) return;
        float acc[8][4];
#pragma unroll
        for (int r = 0; r < 8; ++r)
#pragma unroll
            for (int c = 0; c < 4; ++c) acc[r][c] = 0.f;
#pragma unroll 4
        for (int f = 0; f < 64; ++f) {
            const float4 w4 = *(const float4*)&Wd2[(size_t)f * 2400 + m0];
            const float4 h0 = *(const float4*)&sm.hl[f * 32 + gn * 8];
            const float4 h1 = *(const float4*)&sm.hl[f * 32 + gn * 8 + 4];
            const float hv[8] = {h0.x, h0.y, h0.z, h0.w, h1.x, h1.y, h1.z, h1.w};
            const float wv[4] = {w4.x, w4.y, w4.z, w4.w};
#pragma unroll
            for (int r = 0; r < 8; ++r)
#pragma unroll
                for (int c = 0; c < 4; ++c) acc[r][c] = fmaf(hv[r], wv[c], acc[r][c]);
        }
        const float4 bb = *(const float4*)&bd2[m0];
#pragma unroll
        for (int r = 0; r < 8; ++r) {
            float4 o;
            o.x = acc[r][0] + bb.x; o.y = acc[r][1] + bb.y;
            o.z = acc[r][2] + bb.z; o.w = acc[r][3] + bb.w;
            *(float4*)&out[OFF_IMU + (size_t)(n0 + gn * 8 + r) * 2400 + m0] = o;
        }
        return;
    }

    // --------------------- k234: seg + attention + transformer ---------------------
    S234& sm = *(S234*)smem;
    const int b = blockIdx.x >> 3;
    const int chunk = blockIdx.x & 7;

    // ---- stage K/V for all 256 keys (independent of segmentation) ----
    {
        const float4 h = *(const float4*)(bridge + (size_t)(tid * 32 + b) * 4);
#pragma unroll
        for (int e = 0; e < 4; ++e) {
            sm.kv[tid][e]     = h.x * Wqkv[16 + e] + h.y * Wqkv[20 + e] + h.z * Wqkv[24 + e] + h.w * Wqkv[28 + e];
            sm.kv[tid][4 + e] = h.x * Wqkv[32 + e] + h.y * Wqkv[36 + e] + h.z * Wqkv[40 + e] + h.w * Wqkv[44 + e];
        }
    }

    // ---- forcast + floss (n = b*256 + tid) ----
    {
        const int n = b * 256 + tid;
        float sh[4], cur[4];
#pragma unroll
        for (int j = 0; j < 4; ++j) {
            sh[j] = (tid == 0) ? 0.0f : bridge[(n - 1) * 4 + j];
            cur[j] = bridge[n * 4 + j];
        }
        const float fm = ((tid == 0) ? 0.0f : 1.0f) * imu_mask[n];
        float flv = 0.0f;
#pragma unroll
        for (int j = 0; j < 4; ++j) {
            float f = b_fc[j];
#pragma unroll
            for (int i = 0; i < 4; ++i) f = fmaf(sh[i], W_fc[i * 4 + j], f);
            out[OFF_FC + n * 4 + j] = f;
            const float d = (f - cur[j]) * fm;
            flv = fmaf(d, d, flv);
        }
        flv *= 0.25f;
        const bool lm = (tid >= 2) && (tid < 254);
        flv = (flv > 0.001f && lm) ? flv : 0.0f;
        out[OFF_FL + n] = flv;
        sm.fl[tid] = flv;
        sm.sp[tid] = 0.0f;
    }
    __syncthreads();

    // ---- segmentation (local) ----
    if (tid < 64) {                       // sel: windows of 4, first-max
        const int base = tid * 4;
        float m = sm.fl[base]; int idx = 0;
#pragma unroll
        for (int i = 1; i < 4; ++i) { float v = sm.fl[base + i]; if (v > m) { m = v; idx = i; } }
#pragma unroll
        for (int i = 0; i < 4; ++i) sm.sel[base + i] = (i == idx) ? m : 0.0f;
    }
    __syncthreads();
    if (tid < 63) {                       // sel2 on sel[2:254)
        const int base = 2 + tid * 4;
        float m = sm.sel[base]; int idx = 0;
#pragma unroll
        for (int i = 1; i < 4; ++i) { float v = sm.sel[base + i]; if (v > m) { m = v; idx = i; } }
        sm.sp[base + idx] = (m > 0.0f) ? 1.0f : 0.0f;
    }
    __syncthreads();
    int last = (int)rintf((float)imu_len[b] * (1.0f / 256.0f));  // half-even
    last = imin(imax(last, 2), 256);
    const int point = ((sm.sp[tid] > 0.0f) && (tid < last)) ? 1 : 0;
    sm.pk[tid] = point;
    __syncthreads();
    const int pnext = (tid < 255) ? sm.pk[tid + 1] : 0;
    const int bnd = pnext | ((tid + 1 == last) ? 1 : 0);
    const int kept = (point && !bnd) ? 1 : 0;
    __syncthreads();
    sm.sc[0][tid] = kept;
    __syncthreads();
    int src = 0;                          // Hillis-Steele inclusive scan
    for (int off = 1; off < 256; off <<= 1) {
        const int v = sm.sc[src][tid] + ((tid >= off) ? sm.sc[src][tid - off] : 0);
        sm.sc[src ^ 1][tid] = v;
        __syncthreads();
        src ^= 1;
    }
    const int myid = sm.sc[src][tid];
    sm.sid[tid] = myid;
    const int nk = sm.sc[src][255];
    if (kept) sm.kpl[myid - 1] = tid;
    __syncthreads();
    if (tid < 130) {                      // redundant across the 8 b-blocks
        ends_ws[b * 130 + tid] = (tid < nk) ? sm.kpl[tid] : last;
        starts_ws[b * 130 + tid] = (tid == 0) ? 0 : ((tid - 1 < nk) ? sm.kpl[tid - 1] : last);
    }
    if (tid == 0) nk_ws[b] = nk;

    // ---- attention ----
    const int lq = tid & 31;
    const int jg = tid >> 5;
    const int sq = chunk * 32 + lq;
    {
        const float4 h = *(const float4*)(bridge + (size_t)(sq * 32 + b) * 4);
        float qv[4];
#pragma unroll
        for (int e = 0; e < 4; ++e)
            qv[e] = h.x * Wqkv[e] + h.y * Wqkv[4 + e] + h.z * Wqkv[8 + e] + h.w * Wqkv[12 + e];
        const bool vs = sq < last;
        const int ms = sm.sid[sq];
        const float isq = 0.70710678118654752f;
        float m0 = -1e30f, l0 = 0.f, a00 = 0.f, a01 = 0.f;
        float m1 = -1e30f, l1 = 0.f, a10 = 0.f, a11 = 0.f;
#pragma unroll 4
        for (int jj = 0; jj < 32; ++jj) {
            const int j = jg * 32 + jj;
            const bool allowed = (j == sq) || (vs && (j < last) && (sm.sid[j] == ms));
            const float sc0 = (qv[0] * sm.kv[j][0] + qv[1] * sm.kv[j][1]) * isq;
            const float sc1 = (qv[2] * sm.kv[j][2] + qv[3] * sm.kv[j][3]) * isq;
            {
                const float mn = allowed ? fmaxf(m0, sc0) : m0;
                const float c = __expf(m0 - mn);                      // arg <= 0 always
                const float e = allowed ? __expf(sc0 - mn) : 0.0f;    // select: no inf*0
                l0 = l0 * c + e; a00 = a00 * c + e * sm.kv[j][4]; a01 = a01 * c + e * sm.kv[j][5]; m0 = mn;
            }
            {
                const float mn = allowed ? fmaxf(m1, sc1) : m1;
                const float c = __expf(m1 - mn);
                const float e = allowed ? __expf(sc1 - mn) : 0.0f;
                l1 = l1 * c + e; a10 = a10 * c + e * sm.kv[j][6]; a11 = a11 * c + e * sm.kv[j][7]; m1 = mn;
            }
        }
        float* pp = sm.part[lq][jg];
        pp[0] = m0; pp[1] = l0; pp[2] = a00; pp[3] = a01;
        pp[4] = m1; pp[5] = l1; pp[6] = a10; pp[7] = a11;
    }
    __syncthreads();
    if (tid < 32) {
        const int s = chunk * 32 + tid;
        float M0 = -1e30f, L0 = 0.f, A00 = 0.f, A01 = 0.f;
        float M1 = -1e30f, L1 = 0.f, A10 = 0.f, A11 = 0.f;
#pragma unroll
        for (int p = 0; p < 8; ++p) {
            const float* pp = sm.part[tid][p];
            {
                const float mn = fmaxf(M0, pp[0]);
                const float c0 = __expf(M0 - mn), c1 = __expf(pp[0] - mn);   // args <= 0
                L0 = L0 * c0 + pp[1] * c1; A00 = A00 * c0 + pp[2] * c1; A01 = A01 * c0 + pp[3] * c1; M0 = mn;
            }
            {
                const float mn = fmaxf(M1, pp[4]);
                const float c0 = __expf(M1 - mn), c1 = __expf(pp[4] - mn);
                L1 = L1 * c0 + pp[5] * c1; A10 = A10 * c0 + pp[6] * c1; A11 = A11 * c0 + pp[7] * c1; M1 = mn;
            }
        }
        const float4 h = *(const float4*)(bridge + (size_t)(s * 32 + b) * 4);
        const float hb0 = h.x, hb1 = h.y, hb2 = h.z, hb3 = h.w;
        float ao[4] = {A00 / L0, A01 / L0, A10 / L1, A11 / L1};
        float x1[4];
#pragma unroll
        for (int jj = 0; jj < 4; ++jj)
            x1[jj] = ao[0] * Wo[jj] + ao[1] * Wo[4 + jj] + ao[2] * Wo[8 + jj] + ao[3] * Wo[12 + jj];
        x1[0] += hb0; x1[1] += hb1; x1[2] += hb2; x1[3] += hb3;
        float mean = 0.25f * (x1[0] + x1[1] + x1[2] + x1[3]);
        float var = 0.f;
#pragma unroll
        for (int i = 0; i < 4; ++i) { float d = x1[i] - mean; var += d * d; }
        var *= 0.25f;
        const float rs1 = rsqrtf(var + 1e-5f);
        float h1v[4];
#pragma unroll
        for (int i = 0; i < 4; ++i) h1v[i] = (x1[i] - mean) * rs1 * ln1_g[i] + ln1_b[i];
        float o2[4] = {bf2[0], bf2[1], bf2[2], bf2[3]};
#pragma unroll
        for (int kk = 0; kk < 16; ++kk) {
            float t = bf1[kk];
#pragma unroll
            for (int i = 0; i < 4; ++i) t = fmaf(h1v[i], Wf1[i * 16 + kk], t);
            t = fmaxf(t, 0.0f);
#pragma unroll
            for (int jj = 0; jj < 4; ++jj) o2[jj] = fmaf(t, Wf2[kk * 4 + jj], o2[jj]);
        }
        float x2[4];
#pragma unroll
        for (int i = 0; i < 4; ++i) x2[i] = h1v[i] + o2[i];
        float mean2 = 0.25f * (x2[0] + x2[1] + x2[2] + x2[3]);
        float var2 = 0.f;
#pragma unroll
        for (int i = 0; i < 4; ++i) { float d = x2[i] - mean2; var2 += d * d; }
        var2 *= 0.25f;
        const float rs2 = rsqrtf(var2 + 1e-5f);
        float h2v[4];
#pragma unroll
        for (int i = 0; i < 4; ++i) h2v[i] = (x2[i] - mean2) * rs2 * ln2_g[i] + ln2_b[i];
        float* tp = tr_ws + ((size_t)(b * 256 + s)) * 32;
#pragma unroll
        for (int mm = 0; mm < 32; ++mm)
            tp[mm] = bout[mm] + h2v[0] * Wout[mm] + h2v[1] * Wout[32 + mm]
                   + h2v[2] * Wout[64 + mm] + h2v[3] * Wout[96 + mm];
    }
}

// ============================================================================
// K5: atoms: atom_gen = (emb @ Wa + ba)*valid ; seg_interp gather from x
// grid (130, 32), 128 threads (120 active: d*20+i)
// ============================================================================
__global__ __launch_bounds__(128) void k5_atoms(
    const float* __restrict__ x, const float* __restrict__ tr_ws,
    const int* __restrict__ ends_ws, const int* __restrict__ starts_ws,
    const int* __restrict__ nk_ws,
    const float* __restrict__ Wa, const float* __restrict__ ba,
    float* __restrict__ out)
{
    const int a = blockIdx.x;
    const int b = blockIdx.y;
    const int tid = threadIdx.x;
    __shared__ float emb[32];
    const int e = ends_ws[b * 130 + a];
    const int st = starts_ws[b * 130 + a];
    const int nk = nk_ws[b];
    const float valid = (a <= nk) ? 1.0f : 0.0f;
    const int ec = imin(imax(e - 1, 0), 255);
    if (tid < 32) emb[tid] = tr_ws[((size_t)(b * 256 + ec)) * 32 + tid];
    __syncthreads();
    if (tid < 120) {
        float v = ba[tid];
#pragma unroll
        for (int f = 0; f < 32; ++f) v = fmaf(emb[f], Wa[f * 120 + tid], v);
        out[OFF_ATOM + ((size_t)(b * 130 + a)) * 120 + tid] = v * valid;
        const int d = tid / 20, i = tid % 20;
        const int ilen = (e - st) * 400;
        int idx = st * 400 + (i * ilen) / 20;
        idx = imin(imax(idx, 0), 102399);
        const int si = idx / 400, ti = idx % 400;
        const float px = x[(((size_t)b * 256 + si) * 6 + d) * 400 + ti];
        out[OFF_SEG + ((size_t)(b * 130 + a)) * 120 + tid] = px * valid;
    }
}

// ============================================================================
extern "C" void kernel_launch(void* const* d_in, const int* in_sizes, int n_in,
                              void* d_out, int out_size, void* d_ws, size_t ws_size,
                              hipStream_t stream)
{
    const float* x        = (const float*)d_in[0];
    const float* imu_mask = (const float*)d_in[1];
    const int*   imu_len  = (const int*)  d_in[2];
    const float* conv_w   = (const float*)d_in[3];
    const float* conv_b   = (const float*)d_in[4];
    const float* W_b1     = (const float*)d_in[5];
    const float* b_b1     = (const float*)d_in[6];
    const float* W_fc     = (const float*)d_in[7];
    const float* b_fc     = (const float*)d_in[8];
    const float* Wqkv     = (const float*)d_in[9];
    const float* Wo       = (const float*)d_in[10];
    const float* ln1_g    = (const float*)d_in[11];
    const float* ln1_b    = (const float*)d_in[12];
    const float* Wf1      = (const float*)d_in[13];
    const float* bf1      = (const float*)d_in[14];
    const float* Wf2      = (const float*)d_in[15];
    const float* bf2      = (const float*)d_in[16];
    const float* ln2_g    = (const float*)d_in[17];
    const float* ln2_b    = (const float*)d_in[18];
    const float* Wout     = (const float*)d_in[19];
    const float* bout     = (const float*)d_in[20];
    const float* Wd1      = (const float*)d_in[21];
    const float* bd1      = (const float*)d_in[22];
    const float* Wd2      = (const float*)d_in[23];
    const float* bd2      = (const float*)d_in[24];
    const float* Wa       = (const float*)d_in[25];
    const float* ba       = (const float*)d_in[26];

    float* out = (float*)d_out;
    float* wsf = (float*)d_ws;
    int*   wsi = (int*)d_ws;

    float* bridge = wsf + WS_BRIDGE;
    float* tr_ws  = wsf + WS_TR;
    int* ends   = wsi + WS_ENDS;
    int* starts = wsi + WS_STARTS;
    int* nk     = wsi + WS_NK;

    k1_conv_bridge<<<4096, 128, 0, stream>>>(x, conv_w, conv_b, W_b1, b_b1, bridge);
    k2346_attn_imu<<<2816, 256, 0, stream>>>(bridge, imu_mask, W_fc, b_fc, imu_len,
                                             out, ends, starts, nk,
                                             Wqkv, Wo, ln1_g, ln1_b, Wf1, bf1,
                                             Wf2, bf2, ln2_g, ln2_b, Wout, bout,
                                             tr_ws, Wd1, bd1, Wd2, bd2);
    k5_atoms<<<dim3(130, 32), 128, 0, stream>>>(x, tr_ws, ends, starts, nk, Wa, ba, out);
}